// Round 4
// baseline (191.692 us; speedup 1.0000x reference)
//
#include <hip/hip_runtime.h>
#include <hip/hip_bf16.h>

typedef __attribute__((ext_vector_type(4))) float f32x4;
typedef __attribute__((ext_vector_type(8))) __bf16 bf16x8;
typedef __attribute__((ext_vector_type(8))) unsigned short us8;
typedef __attribute__((ext_vector_type(4))) unsigned int u32x4;

#define LDS_AS __attribute__((address_space(3)))
#define GLB_AS __attribute__((address_space(1)))

__device__ __forceinline__ unsigned short f2bf(float f) {
    unsigned u = __builtin_bit_cast(unsigned, f);
    return (unsigned short)((u + 0x7FFFu + ((u >> 16) & 1u)) >> 16);  // RNE
}
__device__ __forceinline__ float bf2f(unsigned short h) {
    return __builtin_bit_cast(float, (unsigned)h << 16);
}
__device__ __forceinline__ void cp16(const void* g, void* l) {
    __builtin_amdgcn_global_load_lds((const GLB_AS unsigned int*)g,
                                     (LDS_AS unsigned int*)l, 16, 0, 0);
}

// ---------------------------------------------------------------- prep (+audio)
// weights only now: wf/wv bf16 casts, W1p pad, zero accumulators. Grid-stride.
#define NPREPB 544
#define NTOT 557056
__global__ __launch_bounds__(256) void prep_kernel(
    const float* __restrict__ Wfk, const float* __restrict__ Wfv,
    const float* __restrict__ Wvk, const float* __restrict__ Wvv,
    const float* __restrict__ Wout1, const float* __restrict__ audios, const float* __restrict__ Wav,
    unsigned short* __restrict__ wf, unsigned short* __restrict__ wv,
    float* __restrict__ W1p, float* __restrict__ hacc, float* __restrict__ qz,
    float* __restrict__ a_v, float* __restrict__ a_q_p)
{
    __shared__ float aud[128];
    const int t = threadIdx.x;
    if (blockIdx.x >= NPREPB) {              // audio: a_v = relu(audios @ Wav^T)
        const int b = blockIdx.x - NPREPB;
        if (t < 128) aud[t] = audios[b * 128 + t];
        __syncthreads();
        #pragma unroll
        for (int cc = 0; cc < 2; ++cc) {
            int c = 2 * t + cc;
            const float* wr = Wav + (size_t)c * 128;
            float s = 0.f;
            #pragma unroll
            for (int k4 = 0; k4 < 32; ++k4) {
                f32x4 wvv = *(const f32x4*)(wr + k4 * 4);
                s += wvv[0] * aud[k4 * 4] + wvv[1] * aud[k4 * 4 + 1]
                   + wvv[2] * aud[k4 * 4 + 2] + wvv[3] * aud[k4 * 4 + 3];
            }
            s = s > 0.f ? s : 0.f;
            a_v[b * 512 + c] = s;
            a_q_p[b * 512 + c] = s;
        }
        return;
    }
    for (int i = blockIdx.x * 256 + t; i < NTOT; i += NPREPB * 256) {
        int idx = i;
        if (idx < 77824) {                   // wf: 1024 x 76 us8 items (608 cols, pad 600->608)
            int row = idx / 76, k = (idx - row * 76) * 8;
            const float* src = row < 512 ? Wfk + (size_t)row * 600 : Wfv + (size_t)(row - 512) * 600;
            us8 o = {0, 0, 0, 0, 0, 0, 0, 0};
            if (k < 600) {
                f32x4 v0 = *(const f32x4*)(src + k);
                f32x4 v1 = *(const f32x4*)(src + k + 4);
                o[0] = f2bf(v0[0]); o[1] = f2bf(v0[1]); o[2] = f2bf(v0[2]); o[3] = f2bf(v0[3]);
                o[4] = f2bf(v1[0]); o[5] = f2bf(v1[1]); o[6] = f2bf(v1[2]); o[7] = f2bf(v1[3]);
            }
            *(us8*)(wf + (size_t)row * 608 + k) = o;
            continue;
        }
        idx -= 77824;
        if (idx < 98304) {                   // wv: 1024 x 96 us8 items
            int row = idx / 96, k = (idx - row * 96) * 8;
            const float* src = (row < 512 ? Wvk + (size_t)row * 768
                                          : Wvv + (size_t)(row - 512) * 768) + k;
            f32x4 v0 = *(const f32x4*)src;
            f32x4 v1 = *(const f32x4*)(src + 4);
            us8 o = {f2bf(v0[0]), f2bf(v0[1]), f2bf(v0[2]), f2bf(v0[3]),
                     f2bf(v1[0]), f2bf(v1[1]), f2bf(v1[2]), f2bf(v1[3])};
            *(us8*)(wv + (size_t)row * 768 + k) = o;
            continue;
        }
        idx -= 98304;
        if (idx < 344064) {                  // W1p: 768 x 448 f32x4 items (pad 1539->1792)
            int r = idx / 448, k = (idx - r * 448) * 4;
            f32x4 o;
            #pragma unroll
            for (int j = 0; j < 4; ++j) {
                int kk = k + j;
                o[j] = kk < 1539 ? Wout1[(size_t)r * 1539 + kk] : 0.f;
            }
            *(f32x4*)(W1p + (size_t)r * 1792 + k) = o;
            continue;
        }
        idx -= 344064;
        if (idx < 20480) {                   // zero h1acc+h2acc
            f32x4 z = {0, 0, 0, 0};
            *(f32x4*)(hacc + (size_t)idx * 4) = z;
            continue;
        }
        idx -= 20480;
        {                                    // zero f_q_p|v_q_p
            f32x4 z = {0, 0, 0, 0};
            *(f32x4*)(qz + (size_t)idx * 4) = z;
        }
    }
}

// ---------------------------------------------------------------- GEMM, fp32-A fused cast,
// 2-phase double-buffered LDS, T1 XCD swizzle.
// C[m][n] = relu(sum_k A[m][k]*B[n][k]) bf16; value-half column sums -> qout.
__global__ __launch_bounds__(256) void gemm_fused(
    const float* __restrict__ Afp, int Kreal,
    const unsigned short* __restrict__ B,
    unsigned short* __restrict__ C, int Kp, float* __restrict__ qout, int gshift)
{
    __shared__ alignas(16) unsigned short sA[2 * 4096];   // [buf][128 rows][32 cols]
    __shared__ alignas(16) unsigned short sB[2 * 4096];
    const int t = threadIdx.x;
    const int w = t >> 6, l = t & 63;
    const int nwg = gridDim.x;
    const int swz = (blockIdx.x & 7) * (nwg >> 3) + (blockIdx.x >> 3);
    const int bm = swz >> 3, bn = swz & 7;
    const int m0 = bm << 7, n0 = bn << 7;

    // B staging via global_load_lds (wave-uniform base + lane*16)
    const int srow = t >> 2, sk0 = (t & 3) << 3;
    const unsigned short* gB = B + (size_t)(n0 + srow) * Kp + sk0;
    // A staging via registers (fp32 -> bf16 cast fused)
    const int arow = t >> 1, ac0 = (t & 1) << 4;
    const float* gA = Afp + (size_t)(m0 + arow) * Kreal + ac0;

    const int wr = w >> 1, wc = w & 1;
    const int ksteps = Kp >> 5;

    f32x4 av[4];
    // ---- prologue: stage kt=0 into buf 0
    {
        char* lB = (char*)sB + w * 1024;
        cp16(gB, lB);
        cp16(gB + (size_t)64 * Kp, lB + 4096);
        #pragma unroll
        for (int j = 0; j < 4; ++j) {
            int c = ac0 + j * 4;
            av[j] = (c < Kreal) ? *(const f32x4*)(gA + j * 4) : f32x4{0.f, 0.f, 0.f, 0.f};
        }
        unsigned short* dA = sA + arow * 32 + ac0;
        #pragma unroll
        for (int h = 0; h < 2; ++h) {
            us8 o;
            #pragma unroll
            for (int e = 0; e < 8; ++e) {
                float f = av[h * 2 + (e >> 2)][e & 3];
                o[e] = __builtin_bit_cast(unsigned short, __float2bfloat16(f));
            }
            *(us8*)(dA + h * 8) = o;
        }
    }
    __syncthreads();

    f32x4 acc[4][4] = {};
    int cur = 0;
    for (int kt = 0; kt < ksteps; ++kt) {
        const bool more = (kt + 1 < ksteps);
        if (more) {
            // issue next-tile loads first: they fly under this tile's MFMAs
            const unsigned short* gb = gB + (kt + 1) * 32;
            char* lB = (char*)sB + (cur ^ 1) * 8192 + w * 1024;
            cp16(gb, lB);
            cp16(gb + (size_t)64 * Kp, lB + 4096);
            #pragma unroll
            for (int j = 0; j < 4; ++j) {
                int c = (kt + 1) * 32 + ac0 + j * 4;
                av[j] = (c < Kreal) ? *(const f32x4*)(gA + (kt + 1) * 32 + j * 4)
                                    : f32x4{0.f, 0.f, 0.f, 0.f};
            }
        }
        const unsigned short* pA = sA + cur * 4096 + (wr * 64 + (l & 15)) * 32 + ((l >> 4) << 3);
        const unsigned short* pB = sB + cur * 4096 + (wc * 64 + (l & 15)) * 32 + ((l >> 4) << 3);
        bf16x8 af[4], bfr[4];
        #pragma unroll
        for (int i = 0; i < 4; ++i) {
            af[i]  = *(const bf16x8*)(pA + i * 512);
            bfr[i] = *(const bf16x8*)(pB + i * 512);
        }
        #pragma unroll
        for (int mi = 0; mi < 4; ++mi)
            #pragma unroll
            for (int ni = 0; ni < 4; ++ni)
                acc[mi][ni] = __builtin_amdgcn_mfma_f32_16x16x32_bf16(af[mi], bfr[ni], acc[mi][ni], 0, 0, 0);
        if (more) {
            unsigned short* dA = sA + (cur ^ 1) * 4096 + arow * 32 + ac0;
            #pragma unroll
            for (int h = 0; h < 2; ++h) {
                us8 o;
                #pragma unroll
                for (int e = 0; e < 8; ++e) {
                    float f = av[h * 2 + (e >> 2)][e & 3];
                    o[e] = __builtin_bit_cast(unsigned short, __float2bfloat16(f));
                }
                *(us8*)(dA + h * 8) = o;
            }
        }
        __syncthreads();
        cur ^= 1;
    }

    const int crow0 = m0 + wr * 64 + ((l >> 4) << 2);
    const int ccol0 = n0 + wc * 64 + (l & 15);
    #pragma unroll
    for (int mi = 0; mi < 4; ++mi)
        #pragma unroll
        for (int ni = 0; ni < 4; ++ni)
            #pragma unroll
            for (int j = 0; j < 4; ++j) {
                float v = acc[mi][ni][j];
                v = v > 0.f ? v : 0.f;
                C[(size_t)(crow0 + mi * 16 + j) * 1024 + (ccol0 + ni * 16)] = f2bf(v);
            }
    // fused per-group column sums of the value half
    if (n0 >= 512) {
        const int g = m0 >> gshift;
        float csum[4];
        #pragma unroll
        for (int ni = 0; ni < 4; ++ni) {
            float s = 0.f;
            #pragma unroll
            for (int mi = 0; mi < 4; ++mi)
                #pragma unroll
                for (int j = 0; j < 4; ++j)
                    s += fmaxf(acc[mi][ni][j], 0.f);
            s += __shfl_xor(s, 16, 64);
            s += __shfl_xor(s, 32, 64);
            csum[ni] = s;
        }
        if (l < 16) {
            #pragma unroll
            for (int ni = 0; ni < 4; ++ni)
                atomicAdd(&qout[g * 512 + (ccol0 - 512) + ni * 16], csum[ni]);
        }
    }
}

// ---------------------------------------------------------------- scores: one wave per frame
// sbuf[frame] = dot(K_half[frame], v_q_p[g]) / 512. Blocks 0..63 also zero fc|vc.
__global__ __launch_bounds__(256) void scores_kernel(
    const unsigned short* __restrict__ Cf, const unsigned short* __restrict__ Cv,
    const float* __restrict__ v_q_p, float* __restrict__ sbuf, float* __restrict__ fvz)
{
    const int t = threadIdx.x, bid = blockIdx.x;
    if (bid < 64) {                          // zero fc|vc (65536 floats)
        f32x4 z = {0, 0, 0, 0};
        ((f32x4*)fvz)[bid * 256 + t] = z;
    }
    const int w = t >> 6, l = t & 63;
    int frame, g, soff;
    const unsigned short* X;
    if (bid < 4096) { frame = bid * 4 + w; g = frame >> 8; X = Cf; soff = 0; }
    else            { frame = (bid - 4096) * 4 + w; g = frame >> 7; X = Cv; soff = 16384; }
    const float* vq = v_q_p + g * 512 + l * 8;
    f32x4 q0 = *(const f32x4*)vq;
    f32x4 q1 = *(const f32x4*)(vq + 4);
    u32x4 u = *(const u32x4*)(X + (size_t)frame * 1024 + l * 8);
    float acc = q0[0] * bf2f((unsigned short)(u[0] & 0xffff)) + q0[1] * bf2f((unsigned short)(u[0] >> 16))
              + q0[2] * bf2f((unsigned short)(u[1] & 0xffff)) + q0[3] * bf2f((unsigned short)(u[1] >> 16))
              + q1[0] * bf2f((unsigned short)(u[2] & 0xffff)) + q1[1] * bf2f((unsigned short)(u[2] >> 16))
              + q1[2] * bf2f((unsigned short)(u[3] & 0xffff)) + q1[3] * bf2f((unsigned short)(u[3] >> 16));
    #pragma unroll
    for (int m = 1; m < 64; m <<= 1) acc += __shfl_xor(acc, m, 64);
    if (l == 0) sbuf[soff + frame] = acc * (1.f / 512.f);
}

// ---------------------------------------------------------------- PV: softmax + weighted V sum
__global__ __launch_bounds__(256) void pv_kernel(
    const unsigned short* __restrict__ Cf, const unsigned short* __restrict__ Cv,
    const float* __restrict__ sbuf, float* __restrict__ fc, float* __restrict__ vc)
{
    __shared__ float ws[256];
    __shared__ float red[256];
    const int t = threadIdx.x, bid = blockIdx.x;
    int g, chunk, NF, soff;
    const unsigned short* X;
    float* outp;
    if (bid < 512) { g = bid >> 3; chunk = bid & 7; NF = 256; X = Cf; soff = g * 256; outp = fc; }
    else { int b2 = bid - 512; g = b2 >> 2; chunk = b2 & 3; NF = 128; X = Cv; soff = 16384 + g * 128; outp = vc; }
    float s = (t < NF) ? sbuf[soff + t] : -1e30f;
    red[t] = s;
    __syncthreads();
    for (int st = 128; st > 0; st >>= 1) { if (t < st) red[t] = fmaxf(red[t], red[t + st]); __syncthreads(); }
    float m = red[0];
    __syncthreads();
    float e = (t < NF) ? __expf(s - m) : 0.f;
    ws[t] = e;
    red[t] = e;
    __syncthreads();
    for (int st = 128; st > 0; st >>= 1) { if (t < st) red[t] += red[t + st]; __syncthreads(); }
    float inv = 1.f / red[0];
    const int f0 = g * NF + chunk * 32;
    const unsigned int* q = (const unsigned int*)X + (size_t)f0 * 512 + 256 + t;
    float s0 = 0.f, s1 = 0.f;
    #pragma unroll 4
    for (int f = 0; f < 32; ++f) {
        float a = ws[chunk * 32 + f];
        unsigned u = q[(size_t)f * 512];
        s0 += a * bf2f((unsigned short)(u & 0xffff));
        s1 += a * bf2f((unsigned short)(u >> 16));
    }
    atomicAdd(&outp[g * 512 + 2 * t],     s0 * inv);
    atomicAdd(&outp[g * 512 + 2 * t + 1], s1 * inv);
}

// ---------------------------------------------------------------- batched GEMV body
__device__ __forceinline__ void gemv_body(
    const float* __restrict__ X, int ldx, int dorelu,
    const float* __restrict__ W, int ldw, float* __restrict__ Y, int ldy,
    int nc, int kc, int bc)
{
    __shared__ float xs[4096];
    const int t = threadIdx.x;
    #pragma unroll
    for (int j = 0; j < 16; ++j) {
        int idx = t + j * 256;
        float v = X[(size_t)(bc * 32 + (idx >> 7)) * ldx + kc * 128 + (idx & 127)];
        xs[idx] = dorelu ? (v > 0.f ? v : 0.f) : v;
    }
    __syncthreads();
    const int r = t & 63, bg = t >> 6;
    const int row = nc * 64 + r;
    const float* wrow = W + (size_t)row * ldw + kc * 128;
    float acc[8] = {};
    #pragma unroll 8
    for (int k4 = 0; k4 < 32; ++k4) {
        f32x4 wvv = *(const f32x4*)(wrow + k4 * 4);
        #pragma unroll
        for (int bb = 0; bb < 8; ++bb) {
            f32x4 xv = *(const f32x4*)(xs + (bg * 8 + bb) * 128 + k4 * 4);
            acc[bb] += wvv[0] * xv[0] + wvv[1] * xv[1] + wvv[2] * xv[2] + wvv[3] * xv[3];
        }
    }
    #pragma unroll
    for (int bb = 0; bb < 8; ++bb)
        atomicAdd(&Y[(size_t)(bc * 32 + bg * 8 + bb) * ldy + row], acc[bb]);
}

// update: 3 ops x 8 nc x 4 kc x 2 bc = 192 blocks
__global__ __launch_bounds__(256) void update_kernel(
    const float* __restrict__ Wff_f, const float* __restrict__ Wff_v, const float* __restrict__ Wff_a,
    int iter, const float* __restrict__ fc, const float* __restrict__ vc, const float* __restrict__ a_v,
    float* __restrict__ f_q_p, float* __restrict__ v_q_p, float* __restrict__ a_q_p)
{
    int id = blockIdx.x;
    const int op = id >> 6; id &= 63;
    const int nc = id & 7, kc = (id >> 3) & 3, bc = id >> 5;
    const float* W = (op == 0 ? Wff_f : op == 1 ? Wff_v : Wff_a) + (size_t)iter * 262144;
    const float* X = op == 0 ? fc : op == 1 ? vc : a_v;
    float* Y = op == 0 ? f_q_p : op == 1 ? v_q_p : a_q_p;
    gemv_body(X, 512, 0, W, 512, Y, 512, nc, kc, bc);
}

// generic: grid = NC*KC*2
__global__ __launch_bounds__(256) void gemvb_kernel(
    const float* __restrict__ X, int ldx, int dorelu,
    const float* __restrict__ W, int ldw, float* __restrict__ Y, int ldy,
    int NC, int KC)
{
    int bid = blockIdx.x;
    const int nc = bid % NC; bid /= NC;
    const int kc = bid % KC;
    const int bc = bid / KC;
    gemv_body(X, ldx, dorelu, W, ldw, Y, ldy, nc, kc, bc);
}

// ---------------------------------------------------------------- normalize + build feats
__global__ __launch_bounds__(512) void normfeats_kernel(
    const float* __restrict__ a_q_p, const float* __restrict__ f_q_p, const float* __restrict__ v_q_p,
    const float* __restrict__ metas, float* __restrict__ feats)
{
    __shared__ float red[512];
    const int t = threadIdx.x, b = blockIdx.x;
    float a = a_q_p[b * 512 + t];
    red[t] = a;
    __syncthreads();
    for (int s = 256; s > 0; s >>= 1) { if (t < s) red[t] += red[t + s]; __syncthreads(); }
    float mean = red[0] * (1.f / 512.f);
    __syncthreads();
    float d = a - mean;
    red[t] = d * d;
    __syncthreads();
    for (int s = 256; s > 0; s >>= 1) { if (t < s) red[t] += red[t + s]; __syncthreads(); }
    float sd = sqrtf(red[0] * (1.f / 511.f));
    float* fr = feats + (size_t)b * 1792;
    fr[t]        = f_q_p[b * 512 + t];
    fr[512 + t]  = v_q_p[b * 512 + t];
    fr[1024 + t] = d / sd;
    if (t < 256) {
        float v = 0.f;
        if (t == 0) v = metas[b * 5 + 1] * (1.f / 1500.f);
        else if (t == 1) v = metas[b * 5 + 4] * 0.2f;
        else if (t == 2) {
            float du = metas[b * 5 + 3] - metas[b * 5 + 2];
            v = (du > 8000.f ? 100.f : du) * 0.01f;
        }
        fr[1536 + t] = v;
    }
}

// ---------------------------------------------------------------- MLP layers 3+4
__global__ __launch_bounds__(256) void mlp34_kernel(
    const float* __restrict__ h2acc, const float* __restrict__ W3, const float* __restrict__ W4,
    float* __restrict__ out)
{
    __shared__ float xs[512];
    __shared__ float part[256];
    __shared__ float h3[64];
    const int t = threadIdx.x, b = blockIdx.x;
    {
        float v0 = h2acc[(size_t)b * 512 + t];
        float v1 = h2acc[(size_t)b * 512 + 256 + t];
        xs[t] = v0 > 0.f ? v0 : 0.f;
        xs[256 + t] = v1 > 0.f ? v1 : 0.f;
    }
    __syncthreads();
    const int r = t & 63, q = t >> 6;
    const float* wrow = W3 + (size_t)r * 512 + q * 128;
    float acc = 0.f;
    #pragma unroll 8
    for (int k4 = 0; k4 < 32; ++k4) {
        f32x4 wvv = *(const f32x4*)(wrow + k4 * 4);
        f32x4 xv  = *(const f32x4*)(xs + q * 128 + k4 * 4);
        acc += wvv[0] * xv[0] + wvv[1] * xv[1] + wvv[2] * xv[2] + wvv[3] * xv[3];
    }
    part[t] = acc;
    __syncthreads();
    if (t < 64) {
        float h = part[t] + part[t + 64] + part[t + 128] + part[t + 192];
        h3[t] = h > 0.f ? h : 0.f;
    }
    __syncthreads();
    if (t < 64) {
        float v = h3[t] * W4[t];
        #pragma unroll
        for (int m = 1; m < 64; m <<= 1) v += __shfl_xor(v, m, 64);
        if (t == 0) out[b] = 1.f / (1.f + __expf(-v));
    }
}

// ---------------------------------------------------------------- launch
extern "C" void kernel_launch(void* const* d_in, const int* in_sizes, int n_in,
                              void* d_out, int out_size, void* d_ws, size_t ws_size,
                              hipStream_t stream)
{
    const float* metas  = (const float*)d_in[0];
    const float* frames = (const float*)d_in[2];
    const float* vecs   = (const float*)d_in[4];
    const float* audios = (const float*)d_in[6];
    const float* Wfk   = (const float*)d_in[8];
    const float* Wfv   = (const float*)d_in[9];
    const float* Wvk   = (const float*)d_in[10];
    const float* Wvv   = (const float*)d_in[11];
    const float* Wav   = (const float*)d_in[12];
    const float* Wff_f = (const float*)d_in[13];
    const float* Wff_v = (const float*)d_in[14];
    const float* Wff_a = (const float*)d_in[15];
    const float* Wout1 = (const float*)d_in[16];
    const float* Wout2 = (const float*)d_in[17];
    const float* Wout3 = (const float*)d_in[18];
    const float* Wout4 = (const float*)d_in[19];
    float* out = (float*)d_out;

    char* p = (char*)d_ws;
    auto alloc = [&](size_t n) { char* r = p; p += (n + 255) & ~(size_t)255; return r; };
    unsigned short* wf  = (unsigned short*)alloc(1024ull * 608 * 2);
    unsigned short* wv  = (unsigned short*)alloc(1024ull * 768 * 2);
    unsigned short* Cf  = (unsigned short*)alloc(16384ull * 1024 * 2);
    unsigned short* Cv  = (unsigned short*)alloc(8192ull * 1024 * 2);
    float* W1p   = (float*)alloc(768ull * 1792 * 4);
    float* feats = (float*)alloc(64ull * 1792 * 4);
    float* qbuf  = (float*)alloc(2ull * 64 * 512 * 4);     // f_q_p | v_q_p (zeroed in prep)
    float* f_q_p = qbuf;
    float* v_q_p = qbuf + 64 * 512;
    float* a_q_p = (float*)alloc(64ull * 512 * 4);
    float* a_v   = (float*)alloc(64ull * 512 * 4);
    float* fvc   = (float*)alloc(2ull * 64 * 512 * 4);     // fc | vc (zeroed in scores)
    float* fcb   = fvc;
    float* vcb   = fvc + 64 * 512;
    float* hacc  = (float*)alloc(81920ull * 4);            // h1acc (64*768) | h2acc (64*512)
    float* h1acc = hacc;
    float* h2acc = hacc + 64 * 768;
    float* sbuf  = (float*)alloc(24576ull * 4);            // f scores [16384] | v scores [8192]

    prep_kernel<<<NPREPB + 64, 256, 0, stream>>>(Wfk, Wfv, Wvk, Wvv, Wout1, audios, Wav,
                                                 wf, wv, W1p, hacc, qbuf, a_v, a_q_p);
    gemm_fused<<<1024, 256, 0, stream>>>(frames, 600, wf, Cf, 608, f_q_p, 8);
    gemm_fused<<<512, 256, 0, stream>>>(vecs, 768, wv, Cv, 768, v_q_p, 7);
    for (int i = 0; i < 2; ++i) {
        scores_kernel<<<6144, 256, 0, stream>>>(Cf, Cv, v_q_p, sbuf, fvc);
        pv_kernel<<<768, 256, 0, stream>>>(Cf, Cv, sbuf, fcb, vcb);
        update_kernel<<<192, 256, 0, stream>>>(Wff_f, Wff_v, Wff_a, i, fcb, vcb, a_v,
                                               f_q_p, v_q_p, a_q_p);
    }
    normfeats_kernel<<<64, 512, 0, stream>>>(a_q_p, f_q_p, v_q_p, metas, feats);
    gemvb_kernel<<<336, 256, 0, stream>>>(feats, 1792, 0, W1p, 1792, h1acc, 768, 12, 14);
    gemvb_kernel<<<96, 256, 0, stream>>>(h1acc, 768, 1, Wout2, 768, h2acc, 512, 8, 6);
    mlp34_kernel<<<64, 256, 0, stream>>>(h2acc, Wout3, Wout4, out);
}

// Round 5
// 178.135 us; speedup vs baseline: 1.0761x; 1.0761x over previous
//
#include <hip/hip_runtime.h>
#include <hip/hip_bf16.h>

typedef __attribute__((ext_vector_type(4))) float f32x4;
typedef __attribute__((ext_vector_type(8))) __bf16 bf16x8;
typedef __attribute__((ext_vector_type(8))) unsigned short us8;
typedef __attribute__((ext_vector_type(4))) unsigned int u32x4;

#define LDS_AS __attribute__((address_space(3)))
#define GLB_AS __attribute__((address_space(1)))

__device__ __forceinline__ unsigned short f2bf(float f) {
    unsigned u = __builtin_bit_cast(unsigned, f);
    return (unsigned short)((u + 0x7FFFu + ((u >> 16) & 1u)) >> 16);  // RNE
}
__device__ __forceinline__ float bf2f(unsigned short h) {
    return __builtin_bit_cast(float, (unsigned)h << 16);
}
__device__ __forceinline__ void cp16(const void* g, void* l) {
    __builtin_amdgcn_global_load_lds((const GLB_AS unsigned int*)g,
                                     (LDS_AS unsigned int*)l, 16, 0, 0);
}

// ---------------------------------------------------------------- prep (+audio)
// weights only: wf/wv bf16 casts, W1p pad, zero accumulators + zbuf. Grid-stride.
#define NPREPB 544
#define NTOT 557072
__global__ __launch_bounds__(256) void prep_kernel(
    const float* __restrict__ Wfk, const float* __restrict__ Wfv,
    const float* __restrict__ Wvk, const float* __restrict__ Wvv,
    const float* __restrict__ Wout1, const float* __restrict__ audios, const float* __restrict__ Wav,
    unsigned short* __restrict__ wf, unsigned short* __restrict__ wv,
    float* __restrict__ W1p, float* __restrict__ hacc, float* __restrict__ qz,
    float* __restrict__ a_v, float* __restrict__ a_q_p, float* __restrict__ zbuf)
{
    __shared__ float aud[128];
    const int t = threadIdx.x;
    if (blockIdx.x >= NPREPB) {              // audio: a_v = relu(audios @ Wav^T)
        const int b = blockIdx.x - NPREPB;
        if (t < 128) aud[t] = audios[b * 128 + t];
        __syncthreads();
        #pragma unroll
        for (int cc = 0; cc < 2; ++cc) {
            int c = 2 * t + cc;
            const float* wr = Wav + (size_t)c * 128;
            float s = 0.f;
            #pragma unroll
            for (int k4 = 0; k4 < 32; ++k4) {
                f32x4 wvv = *(const f32x4*)(wr + k4 * 4);
                s += wvv[0] * aud[k4 * 4] + wvv[1] * aud[k4 * 4 + 1]
                   + wvv[2] * aud[k4 * 4 + 2] + wvv[3] * aud[k4 * 4 + 3];
            }
            s = s > 0.f ? s : 0.f;
            a_v[b * 512 + c] = s;
            a_q_p[b * 512 + c] = s;
        }
        return;
    }
    for (int i = blockIdx.x * 256 + t; i < NTOT; i += NPREPB * 256) {
        int idx = i;
        if (idx < 77824) {                   // wf: 1024 x 76 us8 items (608 cols, pad 600->608)
            int row = idx / 76, k = (idx - row * 76) * 8;
            const float* src = row < 512 ? Wfk + (size_t)row * 600 : Wfv + (size_t)(row - 512) * 600;
            us8 o = {0, 0, 0, 0, 0, 0, 0, 0};
            if (k < 600) {
                f32x4 v0 = *(const f32x4*)(src + k);
                f32x4 v1 = *(const f32x4*)(src + k + 4);
                o[0] = f2bf(v0[0]); o[1] = f2bf(v0[1]); o[2] = f2bf(v0[2]); o[3] = f2bf(v0[3]);
                o[4] = f2bf(v1[0]); o[5] = f2bf(v1[1]); o[6] = f2bf(v1[2]); o[7] = f2bf(v1[3]);
            }
            *(us8*)(wf + (size_t)row * 608 + k) = o;
            continue;
        }
        idx -= 77824;
        if (idx < 98304) {                   // wv: 1024 x 96 us8 items
            int row = idx / 96, k = (idx - row * 96) * 8;
            const float* src = (row < 512 ? Wvk + (size_t)row * 768
                                          : Wvv + (size_t)(row - 512) * 768) + k;
            f32x4 v0 = *(const f32x4*)src;
            f32x4 v1 = *(const f32x4*)(src + 4);
            us8 o = {f2bf(v0[0]), f2bf(v0[1]), f2bf(v0[2]), f2bf(v0[3]),
                     f2bf(v1[0]), f2bf(v1[1]), f2bf(v1[2]), f2bf(v1[3])};
            *(us8*)(wv + (size_t)row * 768 + k) = o;
            continue;
        }
        idx -= 98304;
        if (idx < 344064) {                  // W1p: 768 x 448 f32x4 items (pad 1539->1792)
            int r = idx / 448, k = (idx - r * 448) * 4;
            f32x4 o;
            #pragma unroll
            for (int j = 0; j < 4; ++j) {
                int kk = k + j;
                o[j] = kk < 1539 ? Wout1[(size_t)r * 1539 + kk] : 0.f;
            }
            *(f32x4*)(W1p + (size_t)r * 1792 + k) = o;
            continue;
        }
        idx -= 344064;
        if (idx < 20480) {                   // zero h1acc+h2acc
            f32x4 z = {0, 0, 0, 0};
            *(f32x4*)(hacc + (size_t)idx * 4) = z;
            continue;
        }
        idx -= 20480;
        if (idx < 16384) {                   // zero f_q_p|v_q_p
            f32x4 z = {0, 0, 0, 0};
            *(f32x4*)(qz + (size_t)idx * 4) = z;
            continue;
        }
        idx -= 16384;
        {                                    // zero zbuf (64 floats)
            f32x4 z = {0, 0, 0, 0};
            *(f32x4*)(zbuf + (size_t)idx * 4) = z;
        }
    }
}

// ---------------------------------------------------------------- GEMM
// A fp32 staged direct-to-LDS via global_load_lds with XOR-swizzled per-lane
// SOURCE addresses (linear dest, m173 pattern); fp32->bf16 at fragment read.
// B bf16 (pre-cast weights) staged linear. 2-phase double buffer, T1 swizzle.
// C[m][n] = relu(sum_k A[m][k]*B[n][k]) bf16; value-half col sums -> qout.
__global__ __launch_bounds__(256) void gemm_fused(
    const float* __restrict__ Afp, int Kreal, int ktiles,
    const unsigned short* __restrict__ B, int Kp,
    unsigned short* __restrict__ C, float* __restrict__ qout, int gshift,
    const float* __restrict__ zbuf)
{
    __shared__ alignas(16) char lds[2][24576];   // per buf: A fp32 16KB | B bf16 8KB
    const int t = threadIdx.x;
    const int w = t >> 6, l = t & 63;
    const int nwg = gridDim.x;
    const int swz = (blockIdx.x & 7) * (nwg >> 3) + (blockIdx.x >> 3);
    const int bm = swz >> 3, bn = swz & 7;
    const int m0 = bm << 7, n0 = bn << 7;

    // A staging: 4 cp16/thread; dest byte q*4096 + t*16 -> row q*32+(t>>3), chunk t&7
    const int arow = t >> 3;
    const int acd = t & 7;
    // B staging: 2 cp16/thread; dest t*16 (+4096) -> row t>>2 (+64), chunk t&3
    const int brow = t >> 2, bc0 = (t & 3) << 3;

    const int wr = w >> 1, wc = w & 1;

    // fragment-read constants
    const int rA = wr * 64 + (l & 15);           // + i*16
    const int keyA = l & 7;
    const int c2 = (l >> 4) << 1;                // logical 16B-chunk base
    const int pa0 = (c2 ^ keyA) << 2;            // float offsets within row
    const int pa1 = ((c2 + 1) ^ keyA) << 2;
    const int pBoff = ((wc * 64 + (l & 15)) << 5) + ((l >> 4) << 3);   // shorts

    auto stage = [&](int buf, int kt) {
        char* base = lds[buf];
        #pragma unroll
        for (int q = 0; q < 4; ++q) {
            int row = q * 32 + arow;
            int sc = acd ^ (row & 7);
            int colf = kt * 32 + sc * 4;
            const float* src = (colf < Kreal)
                ? (Afp + (size_t)(m0 + row) * Kreal + colf) : zbuf;
            cp16(src, base + q * 4096 + w * 1024);
        }
        const unsigned short* gb = B + (size_t)(n0 + brow) * Kp + bc0 + kt * 32;
        cp16(gb, base + 16384 + w * 1024);
        cp16(gb + (size_t)64 * Kp, base + 16384 + 4096 + w * 1024);
    };

    stage(0, 0);
    __syncthreads();

    f32x4 acc[4][4] = {};
    int cur = 0;
    for (int kt = 0; kt < ktiles; ++kt) {
        if (kt + 1 < ktiles) stage(cur ^ 1, kt + 1);   // loads fly under this tile's MFMAs
        const float* fA = (const float*)(lds[cur]);
        const unsigned short* sB = (const unsigned short*)(lds[cur] + 16384);
        bf16x8 af[4], bfr[4];
        #pragma unroll
        for (int i = 0; i < 4; ++i) {
            const float* rp = fA + (size_t)(rA + i * 16) * 32;
            f32x4 lo = *(const f32x4*)(rp + pa0);
            f32x4 hi = *(const f32x4*)(rp + pa1);
            us8 o = {f2bf(lo[0]), f2bf(lo[1]), f2bf(lo[2]), f2bf(lo[3]),
                     f2bf(hi[0]), f2bf(hi[1]), f2bf(hi[2]), f2bf(hi[3])};
            af[i] = __builtin_bit_cast(bf16x8, o);
            bfr[i] = *(const bf16x8*)(sB + pBoff + i * 512);
        }
        #pragma unroll
        for (int mi = 0; mi < 4; ++mi)
            #pragma unroll
            for (int ni = 0; ni < 4; ++ni)
                acc[mi][ni] = __builtin_amdgcn_mfma_f32_16x16x32_bf16(af[mi], bfr[ni], acc[mi][ni], 0, 0, 0);
        __syncthreads();
        cur ^= 1;
    }

    const int crow0 = m0 + wr * 64 + ((l >> 4) << 2);
    const int ccol0 = n0 + wc * 64 + (l & 15);
    #pragma unroll
    for (int mi = 0; mi < 4; ++mi)
        #pragma unroll
        for (int ni = 0; ni < 4; ++ni)
            #pragma unroll
            for (int j = 0; j < 4; ++j) {
                float v = acc[mi][ni][j];
                v = v > 0.f ? v : 0.f;
                C[(size_t)(crow0 + mi * 16 + j) * 1024 + (ccol0 + ni * 16)] = f2bf(v);
            }
    if (n0 >= 512) {                         // fused per-group value-half column sums
        const int g = m0 >> gshift;
        float csum[4];
        #pragma unroll
        for (int ni = 0; ni < 4; ++ni) {
            float s = 0.f;
            #pragma unroll
            for (int mi = 0; mi < 4; ++mi)
                #pragma unroll
                for (int j = 0; j < 4; ++j)
                    s += fmaxf(acc[mi][ni][j], 0.f);
            s += __shfl_xor(s, 16, 64);
            s += __shfl_xor(s, 32, 64);
            csum[ni] = s;
        }
        if (l < 16) {
            #pragma unroll
            for (int ni = 0; ni < 4; ++ni)
                atomicAdd(&qout[g * 512 + (ccol0 - 512) + ni * 16], csum[ni]);
        }
    }
}

// ---------------------------------------------------------------- scores: one wave per frame
__global__ __launch_bounds__(256) void scores_kernel(
    const unsigned short* __restrict__ Cf, const unsigned short* __restrict__ Cv,
    const float* __restrict__ v_q_p, float* __restrict__ sbuf, float* __restrict__ fvz)
{
    const int t = threadIdx.x, bid = blockIdx.x;
    if (bid < 64) {                          // zero fc|vc (65536 floats)
        f32x4 z = {0, 0, 0, 0};
        ((f32x4*)fvz)[bid * 256 + t] = z;
    }
    const int w = t >> 6, l = t & 63;
    int frame, g, soff;
    const unsigned short* X;
    if (bid < 4096) { frame = bid * 4 + w; g = frame >> 8; X = Cf; soff = 0; }
    else            { frame = (bid - 4096) * 4 + w; g = frame >> 7; X = Cv; soff = 16384; }
    const float* vq = v_q_p + g * 512 + l * 8;
    f32x4 q0 = *(const f32x4*)vq;
    f32x4 q1 = *(const f32x4*)(vq + 4);
    u32x4 u = *(const u32x4*)(X + (size_t)frame * 1024 + l * 8);
    float acc = q0[0] * bf2f((unsigned short)(u[0] & 0xffff)) + q0[1] * bf2f((unsigned short)(u[0] >> 16))
              + q0[2] * bf2f((unsigned short)(u[1] & 0xffff)) + q0[3] * bf2f((unsigned short)(u[1] >> 16))
              + q1[0] * bf2f((unsigned short)(u[2] & 0xffff)) + q1[1] * bf2f((unsigned short)(u[2] >> 16))
              + q1[2] * bf2f((unsigned short)(u[3] & 0xffff)) + q1[3] * bf2f((unsigned short)(u[3] >> 16));
    #pragma unroll
    for (int m = 1; m < 64; m <<= 1) acc += __shfl_xor(acc, m, 64);
    if (l == 0) sbuf[soff + frame] = acc * (1.f / 512.f);
}

// ---------------------------------------------------------------- PV: softmax + weighted V sum
__global__ __launch_bounds__(256) void pv_kernel(
    const unsigned short* __restrict__ Cf, const unsigned short* __restrict__ Cv,
    const float* __restrict__ sbuf, float* __restrict__ fc, float* __restrict__ vc)
{
    __shared__ float ws[256];
    __shared__ float red[256];
    const int t = threadIdx.x, bid = blockIdx.x;
    int g, chunk, NF, soff;
    const unsigned short* X;
    float* outp;
    if (bid < 512) { g = bid >> 3; chunk = bid & 7; NF = 256; X = Cf; soff = g * 256; outp = fc; }
    else { int b2 = bid - 512; g = b2 >> 2; chunk = b2 & 3; NF = 128; X = Cv; soff = 16384 + g * 128; outp = vc; }
    float s = (t < NF) ? sbuf[soff + t] : -1e30f;
    red[t] = s;
    __syncthreads();
    for (int st = 128; st > 0; st >>= 1) { if (t < st) red[t] = fmaxf(red[t], red[t + st]); __syncthreads(); }
    float m = red[0];
    __syncthreads();
    float e = (t < NF) ? __expf(s - m) : 0.f;
    ws[t] = e;
    red[t] = e;
    __syncthreads();
    for (int st = 128; st > 0; st >>= 1) { if (t < st) red[t] += red[t + st]; __syncthreads(); }
    float inv = 1.f / red[0];
    const int f0 = g * NF + chunk * 32;
    const unsigned int* q = (const unsigned int*)X + (size_t)f0 * 512 + 256 + t;
    float s0 = 0.f, s1 = 0.f;
    #pragma unroll 4
    for (int f = 0; f < 32; ++f) {
        float a = ws[chunk * 32 + f];
        unsigned u = q[(size_t)f * 512];
        s0 += a * bf2f((unsigned short)(u & 0xffff));
        s1 += a * bf2f((unsigned short)(u >> 16));
    }
    atomicAdd(&outp[g * 512 + 2 * t],     s0 * inv);
    atomicAdd(&outp[g * 512 + 2 * t + 1], s1 * inv);
}

// ---------------------------------------------------------------- batched GEMV body
__device__ __forceinline__ void gemv_body(
    const float* __restrict__ X, int ldx, int dorelu,
    const float* __restrict__ W, int ldw, float* __restrict__ Y, int ldy,
    int nc, int kc, int bc)
{
    __shared__ float xs[4096];
    const int t = threadIdx.x;
    #pragma unroll
    for (int j = 0; j < 16; ++j) {
        int idx = t + j * 256;
        float v = X[(size_t)(bc * 32 + (idx >> 7)) * ldx + kc * 128 + (idx & 127)];
        xs[idx] = dorelu ? (v > 0.f ? v : 0.f) : v;
    }
    __syncthreads();
    const int r = t & 63, bg = t >> 6;
    const int row = nc * 64 + r;
    const float* wrow = W + (size_t)row * ldw + kc * 128;
    float acc[8] = {};
    #pragma unroll 8
    for (int k4 = 0; k4 < 32; ++k4) {
        f32x4 wvv = *(const f32x4*)(wrow + k4 * 4);
        #pragma unroll
        for (int bb = 0; bb < 8; ++bb) {
            f32x4 xv = *(const f32x4*)(xs + (bg * 8 + bb) * 128 + k4 * 4);
            acc[bb] += wvv[0] * xv[0] + wvv[1] * xv[1] + wvv[2] * xv[2] + wvv[3] * xv[3];
        }
    }
    #pragma unroll
    for (int bb = 0; bb < 8; ++bb)
        atomicAdd(&Y[(size_t)(bc * 32 + bg * 8 + bb) * ldy + row], acc[bb]);
}

// update: 3 ops x 8 nc x 4 kc x 2 bc = 192 blocks
__global__ __launch_bounds__(256) void update_kernel(
    const float* __restrict__ Wff_f, const float* __restrict__ Wff_v, const float* __restrict__ Wff_a,
    int iter, const float* __restrict__ fc, const float* __restrict__ vc, const float* __restrict__ a_v,
    float* __restrict__ f_q_p, float* __restrict__ v_q_p, float* __restrict__ a_q_p)
{
    int id = blockIdx.x;
    const int op = id >> 6; id &= 63;
    const int nc = id & 7, kc = (id >> 3) & 3, bc = id >> 5;
    const float* W = (op == 0 ? Wff_f : op == 1 ? Wff_v : Wff_a) + (size_t)iter * 262144;
    const float* X = op == 0 ? fc : op == 1 ? vc : a_v;
    float* Y = op == 0 ? f_q_p : op == 1 ? v_q_p : a_q_p;
    gemv_body(X, 512, 0, W, 512, Y, 512, nc, kc, bc);
}

// generic: grid = NC*KC*2
__global__ __launch_bounds__(256) void gemvb_kernel(
    const float* __restrict__ X, int ldx, int dorelu,
    const float* __restrict__ W, int ldw, float* __restrict__ Y, int ldy,
    int NC, int KC)
{
    int bid = blockIdx.x;
    const int nc = bid % NC; bid /= NC;
    const int kc = bid % KC;
    const int bc = bid / KC;
    gemv_body(X, ldx, dorelu, W, ldw, Y, ldy, nc, kc, bc);
}

// ---------------------------------------------------------------- normalize + build feats
__global__ __launch_bounds__(512) void normfeats_kernel(
    const float* __restrict__ a_q_p, const float* __restrict__ f_q_p, const float* __restrict__ v_q_p,
    const float* __restrict__ metas, float* __restrict__ feats)
{
    __shared__ float red[512];
    const int t = threadIdx.x, b = blockIdx.x;
    float a = a_q_p[b * 512 + t];
    red[t] = a;
    __syncthreads();
    for (int s = 256; s > 0; s >>= 1) { if (t < s) red[t] += red[t + s]; __syncthreads(); }
    float mean = red[0] * (1.f / 512.f);
    __syncthreads();
    float d = a - mean;
    red[t] = d * d;
    __syncthreads();
    for (int s = 256; s > 0; s >>= 1) { if (t < s) red[t] += red[t + s]; __syncthreads(); }
    float sd = sqrtf(red[0] * (1.f / 511.f));
    float* fr = feats + (size_t)b * 1792;
    fr[t]        = f_q_p[b * 512 + t];
    fr[512 + t]  = v_q_p[b * 512 + t];
    fr[1024 + t] = d / sd;
    if (t < 256) {
        float v = 0.f;
        if (t == 0) v = metas[b * 5 + 1] * (1.f / 1500.f);
        else if (t == 1) v = metas[b * 5 + 4] * 0.2f;
        else if (t == 2) {
            float du = metas[b * 5 + 3] - metas[b * 5 + 2];
            v = (du > 8000.f ? 100.f : du) * 0.01f;
        }
        fr[1536 + t] = v;
    }
}

// ---------------------------------------------------------------- MLP layers 3+4
__global__ __launch_bounds__(256) void mlp34_kernel(
    const float* __restrict__ h2acc, const float* __restrict__ W3, const float* __restrict__ W4,
    float* __restrict__ out)
{
    __shared__ float xs[512];
    __shared__ float part[256];
    __shared__ float h3[64];
    const int t = threadIdx.x, b = blockIdx.x;
    {
        float v0 = h2acc[(size_t)b * 512 + t];
        float v1 = h2acc[(size_t)b * 512 + 256 + t];
        xs[t] = v0 > 0.f ? v0 : 0.f;
        xs[256 + t] = v1 > 0.f ? v1 : 0.f;
    }
    __syncthreads();
    const int r = t & 63, q = t >> 6;
    const float* wrow = W3 + (size_t)r * 512 + q * 128;
    float acc = 0.f;
    #pragma unroll 8
    for (int k4 = 0; k4 < 32; ++k4) {
        f32x4 wvv = *(const f32x4*)(wrow + k4 * 4);
        f32x4 xv  = *(const f32x4*)(xs + q * 128 + k4 * 4);
        acc += wvv[0] * xv[0] + wvv[1] * xv[1] + wvv[2] * xv[2] + wvv[3] * xv[3];
    }
    part[t] = acc;
    __syncthreads();
    if (t < 64) {
        float h = part[t] + part[t + 64] + part[t + 128] + part[t + 192];
        h3[t] = h > 0.f ? h : 0.f;
    }
    __syncthreads();
    if (t < 64) {
        float v = h3[t] * W4[t];
        #pragma unroll
        for (int m = 1; m < 64; m <<= 1) v += __shfl_xor(v, m, 64);
        if (t == 0) out[b] = 1.f / (1.f + __expf(-v));
    }
}

// ---------------------------------------------------------------- launch
extern "C" void kernel_launch(void* const* d_in, const int* in_sizes, int n_in,
                              void* d_out, int out_size, void* d_ws, size_t ws_size,
                              hipStream_t stream)
{
    const float* metas  = (const float*)d_in[0];
    const float* frames = (const float*)d_in[2];
    const float* vecs   = (const float*)d_in[4];
    const float* audios = (const float*)d_in[6];
    const float* Wfk   = (const float*)d_in[8];
    const float* Wfv   = (const float*)d_in[9];
    const float* Wvk   = (const float*)d_in[10];
    const float* Wvv   = (const float*)d_in[11];
    const float* Wav   = (const float*)d_in[12];
    const float* Wff_f = (const float*)d_in[13];
    const float* Wff_v = (const float*)d_in[14];
    const float* Wff_a = (const float*)d_in[15];
    const float* Wout1 = (const float*)d_in[16];
    const float* Wout2 = (const float*)d_in[17];
    const float* Wout3 = (const float*)d_in[18];
    const float* Wout4 = (const float*)d_in[19];
    float* out = (float*)d_out;

    char* p = (char*)d_ws;
    auto alloc = [&](size_t n) { char* r = p; p += (n + 255) & ~(size_t)255; return r; };
    unsigned short* wf  = (unsigned short*)alloc(1024ull * 608 * 2);
    unsigned short* wv  = (unsigned short*)alloc(1024ull * 768 * 2);
    unsigned short* Cf  = (unsigned short*)alloc(16384ull * 1024 * 2);
    unsigned short* Cv  = (unsigned short*)alloc(8192ull * 1024 * 2);
    float* W1p   = (float*)alloc(768ull * 1792 * 4);
    float* feats = (float*)alloc(64ull * 1792 * 4);
    float* qbuf  = (float*)alloc(2ull * 64 * 512 * 4);     // f_q_p | v_q_p (zeroed in prep)
    float* f_q_p = qbuf;
    float* v_q_p = qbuf + 64 * 512;
    float* a_q_p = (float*)alloc(64ull * 512 * 4);
    float* a_v   = (float*)alloc(64ull * 512 * 4);
    float* fvc   = (float*)alloc(2ull * 64 * 512 * 4);     // fc | vc (zeroed in scores)
    float* fcb   = fvc;
    float* vcb   = fvc + 64 * 512;
    float* hacc  = (float*)alloc(81920ull * 4);            // h1acc (64*768) | h2acc (64*512)
    float* h1acc = hacc;
    float* h2acc = hacc + 64 * 768;
    float* sbuf  = (float*)alloc(24576ull * 4);            // f scores | v scores
    float* zbuf  = (float*)alloc(64ull * 4);               // zeros for OOB staging lanes

    prep_kernel<<<NPREPB + 64, 256, 0, stream>>>(Wfk, Wfv, Wvk, Wvv, Wout1, audios, Wav,
                                                 wf, wv, W1p, hacc, qbuf, a_v, a_q_p, zbuf);
    gemm_fused<<<1024, 256, 0, stream>>>(frames, 600, 19, wf, 608, Cf, f_q_p, 8, zbuf);
    gemm_fused<<<512, 256, 0, stream>>>(vecs, 768, 24, wv, 768, Cv, v_q_p, 7, zbuf);
    for (int i = 0; i < 2; ++i) {
        scores_kernel<<<6144, 256, 0, stream>>>(Cf, Cv, v_q_p, sbuf, fvc);
        pv_kernel<<<768, 256, 0, stream>>>(Cf, Cv, sbuf, fcb, vcb);
        update_kernel<<<192, 256, 0, stream>>>(Wff_f, Wff_v, Wff_a, i, fcb, vcb, a_v,
                                               f_q_p, v_q_p, a_q_p);
    }
    normfeats_kernel<<<64, 512, 0, stream>>>(a_q_p, f_q_p, v_q_p, metas, feats);
    gemvb_kernel<<<336, 256, 0, stream>>>(feats, 1792, 0, W1p, 1792, h1acc, 768, 12, 14);
    gemvb_kernel<<<96, 256, 0, stream>>>(h1acc, 768, 1, Wout2, 768, h2acc, 512, 8, 6);
    mlp34_kernel<<<64, 256, 0, stream>>>(h2acc, Wout3, Wout4, out);
}

// Round 6
// 172.589 us; speedup vs baseline: 1.1107x; 1.0321x over previous
//
#include <hip/hip_runtime.h>
#include <hip/hip_bf16.h>

typedef __attribute__((ext_vector_type(4))) float f32x4;
typedef __attribute__((ext_vector_type(8))) __bf16 bf16x8;
typedef __attribute__((ext_vector_type(8))) unsigned short us8;
typedef __attribute__((ext_vector_type(4))) unsigned int u32x4;

#define LDS_AS __attribute__((address_space(3)))
#define GLB_AS __attribute__((address_space(1)))

__device__ __forceinline__ unsigned short f2bf(float f) {
    unsigned u = __builtin_bit_cast(unsigned, f);
    return (unsigned short)((u + 0x7FFFu + ((u >> 16) & 1u)) >> 16);  // RNE
}
__device__ __forceinline__ float bf2f(unsigned short h) {
    return __builtin_bit_cast(float, (unsigned)h << 16);
}
__device__ __forceinline__ void cp16(const void* g, void* l) {
    __builtin_amdgcn_global_load_lds((const GLB_AS unsigned int*)g,
                                     (LDS_AS unsigned int*)l, 16, 0, 0);
}

// ---------------------------------------------------------------- prep (+audio)
// weights only: wf/wv bf16 casts, W1p pad, zero accumulators + zbuf. Grid-stride.
#define NPREPB 544
#define NTOT 557072
__global__ __launch_bounds__(256) void prep_kernel(
    const float* __restrict__ Wfk, const float* __restrict__ Wfv,
    const float* __restrict__ Wvk, const float* __restrict__ Wvv,
    const float* __restrict__ Wout1, const float* __restrict__ audios, const float* __restrict__ Wav,
    unsigned short* __restrict__ wf, unsigned short* __restrict__ wv,
    float* __restrict__ W1p, float* __restrict__ hacc, float* __restrict__ qz,
    float* __restrict__ a_v, float* __restrict__ a_q_p, float* __restrict__ zbuf)
{
    __shared__ float aud[128];
    const int t = threadIdx.x;
    if (blockIdx.x >= NPREPB) {              // audio: a_v = relu(audios @ Wav^T)
        const int b = blockIdx.x - NPREPB;
        if (t < 128) aud[t] = audios[b * 128 + t];
        __syncthreads();
        #pragma unroll
        for (int cc = 0; cc < 2; ++cc) {
            int c = 2 * t + cc;
            const float* wr = Wav + (size_t)c * 128;
            float s = 0.f;
            #pragma unroll
            for (int k4 = 0; k4 < 32; ++k4) {
                f32x4 wvv = *(const f32x4*)(wr + k4 * 4);
                s += wvv[0] * aud[k4 * 4] + wvv[1] * aud[k4 * 4 + 1]
                   + wvv[2] * aud[k4 * 4 + 2] + wvv[3] * aud[k4 * 4 + 3];
            }
            s = s > 0.f ? s : 0.f;
            a_v[b * 512 + c] = s;
            a_q_p[b * 512 + c] = s;
        }
        return;
    }
    for (int i = blockIdx.x * 256 + t; i < NTOT; i += NPREPB * 256) {
        int idx = i;
        if (idx < 77824) {                   // wf: 1024 x 76 us8 items (608 cols, pad 600->608)
            int row = idx / 76, k = (idx - row * 76) * 8;
            const float* src = row < 512 ? Wfk + (size_t)row * 600 : Wfv + (size_t)(row - 512) * 600;
            us8 o = {0, 0, 0, 0, 0, 0, 0, 0};
            if (k < 600) {
                f32x4 v0 = *(const f32x4*)(src + k);
                f32x4 v1 = *(const f32x4*)(src + k + 4);
                o[0] = f2bf(v0[0]); o[1] = f2bf(v0[1]); o[2] = f2bf(v0[2]); o[3] = f2bf(v0[3]);
                o[4] = f2bf(v1[0]); o[5] = f2bf(v1[1]); o[6] = f2bf(v1[2]); o[7] = f2bf(v1[3]);
            }
            *(us8*)(wf + (size_t)row * 608 + k) = o;
            continue;
        }
        idx -= 77824;
        if (idx < 98304) {                   // wv: 1024 x 96 us8 items
            int row = idx / 96, k = (idx - row * 96) * 8;
            const float* src = (row < 512 ? Wvk + (size_t)row * 768
                                          : Wvv + (size_t)(row - 512) * 768) + k;
            f32x4 v0 = *(const f32x4*)src;
            f32x4 v1 = *(const f32x4*)(src + 4);
            us8 o = {f2bf(v0[0]), f2bf(v0[1]), f2bf(v0[2]), f2bf(v0[3]),
                     f2bf(v1[0]), f2bf(v1[1]), f2bf(v1[2]), f2bf(v1[3])};
            *(us8*)(wv + (size_t)row * 768 + k) = o;
            continue;
        }
        idx -= 98304;
        if (idx < 344064) {                  // W1p: 768 x 448 f32x4 items (pad 1539->1792)
            int r = idx / 448, k = (idx - r * 448) * 4;
            f32x4 o;
            #pragma unroll
            for (int j = 0; j < 4; ++j) {
                int kk = k + j;
                o[j] = kk < 1539 ? Wout1[(size_t)r * 1539 + kk] : 0.f;
            }
            *(f32x4*)(W1p + (size_t)r * 1792 + k) = o;
            continue;
        }
        idx -= 344064;
        if (idx < 20480) {                   // zero h1acc+h2acc
            f32x4 z = {0, 0, 0, 0};
            *(f32x4*)(hacc + (size_t)idx * 4) = z;
            continue;
        }
        idx -= 20480;
        if (idx < 16384) {                   // zero f_q_p|v_q_p
            f32x4 z = {0, 0, 0, 0};
            *(f32x4*)(qz + (size_t)idx * 4) = z;
            continue;
        }
        idx -= 16384;
        {                                    // zero zbuf (64 floats)
            f32x4 z = {0, 0, 0, 0};
            *(f32x4*)(zbuf + (size_t)idx * 4) = z;
        }
    }
}

// ---------------------------------------------------------------- GEMM
// A fp32 staged direct-to-LDS (global_load_lds, XOR-swizzled per-lane source,
// linear dest); native fp32->bf16 cvt at fragment read. B bf16 staged linear.
// 3-deep pipeline with counted vmcnt (never drains to 0 in the loop).
// C[m][n] = relu(sum_k A[m][k]*B[n][k]) bf16; value-half col sums -> qout.
__global__ __launch_bounds__(256) void gemm_fused(
    const float* __restrict__ Afp, int Kreal, int ktiles,
    const unsigned short* __restrict__ B, int Kp,
    unsigned short* __restrict__ C, float* __restrict__ qout, int gshift,
    const float* __restrict__ zbuf)
{
    __shared__ alignas(16) char lds[3][24576];   // per buf: A fp32 16KB | B bf16 8KB
    const int t = threadIdx.x;
    const int w = t >> 6, l = t & 63;
    const int nwg = gridDim.x;
    const int swz = (blockIdx.x & 7) * (nwg >> 3) + (blockIdx.x >> 3);
    const int bm = swz >> 3, bn = swz & 7;
    const int m0 = bm << 7, n0 = bn << 7;

    // A staging: 4 cp16/thread; dest row q*32+(t>>3), dest chunk t&7 (linear);
    // source chunk XORed by row&7 so the fragment read is bank-balanced.
    const int arow = t >> 3;
    const int acd = t & 7;
    // B staging: 2 cp16/thread
    const int brow = t >> 2, bc0 = (t & 3) << 3;

    const int wr = w >> 1, wc = w & 1;

    // fragment-read constants
    const int rA = wr * 64 + (l & 15);           // + i*16
    const int keyA = l & 7;
    const int c2 = (l >> 4) << 1;                // logical 16B-chunk base
    const int pa0 = (c2 ^ keyA) << 2;            // float offsets within row
    const int pa1 = ((c2 + 1) ^ keyA) << 2;
    const int pBoff = ((wc * 64 + (l & 15)) << 5) + ((l >> 4) << 3);   // shorts

    auto stage = [&](char* base, int kt) {
        #pragma unroll
        for (int q = 0; q < 4; ++q) {
            int row = q * 32 + arow;
            int sc = acd ^ (row & 7);
            int colf = kt * 32 + sc * 4;
            const float* src = (colf < Kreal)
                ? (Afp + (size_t)(m0 + row) * Kreal + colf) : zbuf;
            cp16(src, base + q * 4096 + w * 1024);
        }
        const unsigned short* gb = B + (size_t)(n0 + brow) * Kp + bc0 + kt * 32;
        cp16(gb, base + 16384 + w * 1024);
        cp16(gb + (size_t)64 * Kp, base + 16384 + 4096 + w * 1024);
    };

    // prologue: 2 tiles in flight
    stage(lds[0], 0);
    if (ktiles > 1) stage(lds[1], 1);

    f32x4 acc[4][4] = {};
    int cur = 0;
    for (int kt = 0; kt < ktiles; ++kt) {
        if (kt + 2 < ktiles) {
            int b2 = cur + 2; if (b2 >= 3) b2 -= 3;
            stage(lds[b2], kt + 2);                       // buf freed at end of iter kt-1
            asm volatile("s_waitcnt vmcnt(12)" ::: "memory");   // tile kt landed; 12 in flight
        } else if (kt + 1 < ktiles) {
            asm volatile("s_waitcnt vmcnt(6)" ::: "memory");
        } else {
            asm volatile("s_waitcnt vmcnt(0)" ::: "memory");
        }
        __builtin_amdgcn_sched_barrier(0);
        __builtin_amdgcn_s_barrier();
        __builtin_amdgcn_sched_barrier(0);

        const float* fA = (const float*)(lds[cur]);
        const unsigned short* sB = (const unsigned short*)(lds[cur] + 16384);
        bf16x8 af[4], bfr[4];
        #pragma unroll
        for (int i = 0; i < 4; ++i) {
            const float* rp = fA + (size_t)(rA + i * 16) * 32;
            f32x4 lo = *(const f32x4*)(rp + pa0);
            f32x4 hi = *(const f32x4*)(rp + pa1);
            bf16x8 a;
            a[0] = (__bf16)lo[0]; a[1] = (__bf16)lo[1];
            a[2] = (__bf16)lo[2]; a[3] = (__bf16)lo[3];
            a[4] = (__bf16)hi[0]; a[5] = (__bf16)hi[1];
            a[6] = (__bf16)hi[2]; a[7] = (__bf16)hi[3];
            af[i] = a;
            bfr[i] = *(const bf16x8*)(sB + pBoff + i * 512);
        }
        #pragma unroll
        for (int mi = 0; mi < 4; ++mi)
            #pragma unroll
            for (int ni = 0; ni < 4; ++ni)
                acc[mi][ni] = __builtin_amdgcn_mfma_f32_16x16x32_bf16(af[mi], bfr[ni], acc[mi][ni], 0, 0, 0);

        __builtin_amdgcn_sched_barrier(0);
        __builtin_amdgcn_s_barrier();                     // all waves done reading buf[cur]
        cur = (cur == 2) ? 0 : cur + 1;
    }

    const int crow0 = m0 + wr * 64 + ((l >> 4) << 2);
    const int ccol0 = n0 + wc * 64 + (l & 15);
    #pragma unroll
    for (int mi = 0; mi < 4; ++mi)
        #pragma unroll
        for (int ni = 0; ni < 4; ++ni)
            #pragma unroll
            for (int j = 0; j < 4; ++j) {
                float v = acc[mi][ni][j];
                v = v > 0.f ? v : 0.f;
                C[(size_t)(crow0 + mi * 16 + j) * 1024 + (ccol0 + ni * 16)] = f2bf(v);
            }
    if (n0 >= 512) {                         // fused per-group value-half column sums
        const int g = m0 >> gshift;
        float csum[4];
        #pragma unroll
        for (int ni = 0; ni < 4; ++ni) {
            float s = 0.f;
            #pragma unroll
            for (int mi = 0; mi < 4; ++mi)
                #pragma unroll
                for (int j = 0; j < 4; ++j)
                    s += fmaxf(acc[mi][ni][j], 0.f);
            s += __shfl_xor(s, 16, 64);
            s += __shfl_xor(s, 32, 64);
            csum[ni] = s;
        }
        if (l < 16) {
            #pragma unroll
            for (int ni = 0; ni < 4; ++ni)
                atomicAdd(&qout[g * 512 + (ccol0 - 512) + ni * 16], csum[ni]);
        }
    }
}

// ---------------------------------------------------------------- scores: one wave per frame
__global__ __launch_bounds__(256) void scores_kernel(
    const unsigned short* __restrict__ Cf, const unsigned short* __restrict__ Cv,
    const float* __restrict__ v_q_p, float* __restrict__ sbuf, float* __restrict__ fvz)
{
    const int t = threadIdx.x, bid = blockIdx.x;
    if (bid < 64) {                          // zero fc|vc (65536 floats)
        f32x4 z = {0, 0, 0, 0};
        ((f32x4*)fvz)[bid * 256 + t] = z;
    }
    const int w = t >> 6, l = t & 63;
    int frame, g, soff;
    const unsigned short* X;
    if (bid < 4096) { frame = bid * 4 + w; g = frame >> 8; X = Cf; soff = 0; }
    else            { frame = (bid - 4096) * 4 + w; g = frame >> 7; X = Cv; soff = 16384; }
    const float* vq = v_q_p + g * 512 + l * 8;
    f32x4 q0 = *(const f32x4*)vq;
    f32x4 q1 = *(const f32x4*)(vq + 4);
    u32x4 u = *(const u32x4*)(X + (size_t)frame * 1024 + l * 8);
    float acc = q0[0] * bf2f((unsigned short)(u[0] & 0xffff)) + q0[1] * bf2f((unsigned short)(u[0] >> 16))
              + q0[2] * bf2f((unsigned short)(u[1] & 0xffff)) + q0[3] * bf2f((unsigned short)(u[1] >> 16))
              + q1[0] * bf2f((unsigned short)(u[2] & 0xffff)) + q1[1] * bf2f((unsigned short)(u[2] >> 16))
              + q1[2] * bf2f((unsigned short)(u[3] & 0xffff)) + q1[3] * bf2f((unsigned short)(u[3] >> 16));
    #pragma unroll
    for (int m = 1; m < 64; m <<= 1) acc += __shfl_xor(acc, m, 64);
    if (l == 0) sbuf[soff + frame] = acc * (1.f / 512.f);
}

// ---------------------------------------------------------------- PV: softmax + weighted V sum
__global__ __launch_bounds__(256) void pv_kernel(
    const unsigned short* __restrict__ Cf, const unsigned short* __restrict__ Cv,
    const float* __restrict__ sbuf, float* __restrict__ fc, float* __restrict__ vc)
{
    __shared__ float ws[256];
    __shared__ float red[256];
    const int t = threadIdx.x, bid = blockIdx.x;
    int g, chunk, NF, soff;
    const unsigned short* X;
    float* outp;
    if (bid < 512) { g = bid >> 3; chunk = bid & 7; NF = 256; X = Cf; soff = g * 256; outp = fc; }
    else { int b2 = bid - 512; g = b2 >> 2; chunk = b2 & 3; NF = 128; X = Cv; soff = 16384 + g * 128; outp = vc; }
    float s = (t < NF) ? sbuf[soff + t] : -1e30f;
    red[t] = s;
    __syncthreads();
    for (int st = 128; st > 0; st >>= 1) { if (t < st) red[t] = fmaxf(red[t], red[t + st]); __syncthreads(); }
    float m = red[0];
    __syncthreads();
    float e = (t < NF) ? __expf(s - m) : 0.f;
    ws[t] = e;
    red[t] = e;
    __syncthreads();
    for (int st = 128; st > 0; st >>= 1) { if (t < st) red[t] += red[t + st]; __syncthreads(); }
    float inv = 1.f / red[0];
    const int f0 = g * NF + chunk * 32;
    const unsigned int* q = (const unsigned int*)X + (size_t)f0 * 512 + 256 + t;
    float s0 = 0.f, s1 = 0.f;
    #pragma unroll 4
    for (int f = 0; f < 32; ++f) {
        float a = ws[chunk * 32 + f];
        unsigned u = q[(size_t)f * 512];
        s0 += a * bf2f((unsigned short)(u & 0xffff));
        s1 += a * bf2f((unsigned short)(u >> 16));
    }
    atomicAdd(&outp[g * 512 + 2 * t],     s0 * inv);
    atomicAdd(&outp[g * 512 + 2 * t + 1], s1 * inv);
}

// ---------------------------------------------------------------- batched GEMV body
__device__ __forceinline__ void gemv_body(
    const float* __restrict__ X, int ldx, int dorelu,
    const float* __restrict__ W, int ldw, float* __restrict__ Y, int ldy,
    int nc, int kc, int bc)
{
    __shared__ float xs[4096];
    const int t = threadIdx.x;
    #pragma unroll
    for (int j = 0; j < 16; ++j) {
        int idx = t + j * 256;
        float v = X[(size_t)(bc * 32 + (idx >> 7)) * ldx + kc * 128 + (idx & 127)];
        xs[idx] = dorelu ? (v > 0.f ? v : 0.f) : v;
    }
    __syncthreads();
    const int r = t & 63, bg = t >> 6;
    const int row = nc * 64 + r;
    const float* wrow = W + (size_t)row * ldw + kc * 128;
    float acc[8] = {};
    #pragma unroll 8
    for (int k4 = 0; k4 < 32; ++k4) {
        f32x4 wvv = *(const f32x4*)(wrow + k4 * 4);
        #pragma unroll
        for (int bb = 0; bb < 8; ++bb) {
            f32x4 xv = *(const f32x4*)(xs + (bg * 8 + bb) * 128 + k4 * 4);
            acc[bb] += wvv[0] * xv[0] + wvv[1] * xv[1] + wvv[2] * xv[2] + wvv[3] * xv[3];
        }
    }
    #pragma unroll
    for (int bb = 0; bb < 8; ++bb)
        atomicAdd(&Y[(size_t)(bc * 32 + bg * 8 + bb) * ldy + row], acc[bb]);
}

// update: 3 ops x 8 nc x 4 kc x 2 bc = 192 blocks
__global__ __launch_bounds__(256) void update_kernel(
    const float* __restrict__ Wff_f, const float* __restrict__ Wff_v, const float* __restrict__ Wff_a,
    int iter, const float* __restrict__ fc, const float* __restrict__ vc, const float* __restrict__ a_v,
    float* __restrict__ f_q_p, float* __restrict__ v_q_p, float* __restrict__ a_q_p)
{
    int id = blockIdx.x;
    const int op = id >> 6; id &= 63;
    const int nc = id & 7, kc = (id >> 3) & 3, bc = id >> 5;
    const float* W = (op == 0 ? Wff_f : op == 1 ? Wff_v : Wff_a) + (size_t)iter * 262144;
    const float* X = op == 0 ? fc : op == 1 ? vc : a_v;
    float* Y = op == 0 ? f_q_p : op == 1 ? v_q_p : a_q_p;
    gemv_body(X, 512, 0, W, 512, Y, 512, nc, kc, bc);
}

// generic: grid = NC*KC*2
__global__ __launch_bounds__(256) void gemvb_kernel(
    const float* __restrict__ X, int ldx, int dorelu,
    const float* __restrict__ W, int ldw, float* __restrict__ Y, int ldy,
    int NC, int KC)
{
    int bid = blockIdx.x;
    const int nc = bid % NC; bid /= NC;
    const int kc = bid % KC;
    const int bc = bid / KC;
    gemv_body(X, ldx, dorelu, W, ldw, Y, ldy, nc, kc, bc);
}

// ---------------------------------------------------------------- normalize + build feats
__global__ __launch_bounds__(512) void normfeats_kernel(
    const float* __restrict__ a_q_p, const float* __restrict__ f_q_p, const float* __restrict__ v_q_p,
    const float* __restrict__ metas, float* __restrict__ feats)
{
    __shared__ float red[512];
    const int t = threadIdx.x, b = blockIdx.x;
    float a = a_q_p[b * 512 + t];
    red[t] = a;
    __syncthreads();
    for (int s = 256; s > 0; s >>= 1) { if (t < s) red[t] += red[t + s]; __syncthreads(); }
    float mean = red[0] * (1.f / 512.f);
    __syncthreads();
    float d = a - mean;
    red[t] = d * d;
    __syncthreads();
    for (int s = 256; s > 0; s >>= 1) { if (t < s) red[t] += red[t + s]; __syncthreads(); }
    float sd = sqrtf(red[0] * (1.f / 511.f));
    float* fr = feats + (size_t)b * 1792;
    fr[t]        = f_q_p[b * 512 + t];
    fr[512 + t]  = v_q_p[b * 512 + t];
    fr[1024 + t] = d / sd;
    if (t < 256) {
        float v = 0.f;
        if (t == 0) v = metas[b * 5 + 1] * (1.f / 1500.f);
        else if (t == 1) v = metas[b * 5 + 4] * 0.2f;
        else if (t == 2) {
            float du = metas[b * 5 + 3] - metas[b * 5 + 2];
            v = (du > 8000.f ? 100.f : du) * 0.01f;
        }
        fr[1536 + t] = v;
    }
}

// ---------------------------------------------------------------- MLP layers 3+4
__global__ __launch_bounds__(256) void mlp34_kernel(
    const float* __restrict__ h2acc, const float* __restrict__ W3, const float* __restrict__ W4,
    float* __restrict__ out)
{
    __shared__ float xs[512];
    __shared__ float part[256];
    __shared__ float h3[64];
    const int t = threadIdx.x, b = blockIdx.x;
    {
        float v0 = h2acc[(size_t)b * 512 + t];
        float v1 = h2acc[(size_t)b * 512 + 256 + t];
        xs[t] = v0 > 0.f ? v0 : 0.f;
        xs[256 + t] = v1 > 0.f ? v1 : 0.f;
    }
    __syncthreads();
    const int r = t & 63, q = t >> 6;
    const float* wrow = W3 + (size_t)r * 512 + q * 128;
    float acc = 0.f;
    #pragma unroll 8
    for (int k4 = 0; k4 < 32; ++k4) {
        f32x4 wvv = *(const f32x4*)(wrow + k4 * 4);
        f32x4 xv  = *(const f32x4*)(xs + q * 128 + k4 * 4);
        acc += wvv[0] * xv[0] + wvv[1] * xv[1] + wvv[2] * xv[2] + wvv[3] * xv[3];
    }
    part[t] = acc;
    __syncthreads();
    if (t < 64) {
        float h = part[t] + part[t + 64] + part[t + 128] + part[t + 192];
        h3[t] = h > 0.f ? h : 0.f;
    }
    __syncthreads();
    if (t < 64) {
        float v = h3[t] * W4[t];
        #pragma unroll
        for (int m = 1; m < 64; m <<= 1) v += __shfl_xor(v, m, 64);
        if (t == 0) out[b] = 1.f / (1.f + __expf(-v));
    }
}

// ---------------------------------------------------------------- launch
extern "C" void kernel_launch(void* const* d_in, const int* in_sizes, int n_in,
                              void* d_out, int out_size, void* d_ws, size_t ws_size,
                              hipStream_t stream)
{
    const float* metas  = (const float*)d_in[0];
    const float* frames = (const float*)d_in[2];
    const float* vecs   = (const float*)d_in[4];
    const float* audios = (const float*)d_in[6];
    const float* Wfk   = (const float*)d_in[8];
    const float* Wfv   = (const float*)d_in[9];
    const float* Wvk   = (const float*)d_in[10];
    const float* Wvv   = (const float*)d_in[11];
    const float* Wav   = (const float*)d_in[12];
    const float* Wff_f = (const float*)d_in[13];
    const float* Wff_v = (const float*)d_in[14];
    const float* Wff_a = (const float*)d_in[15];
    const float* Wout1 = (const float*)d_in[16];
    const float* Wout2 = (const float*)d_in[17];
    const float* Wout3 = (const float*)d_in[18];
    const float* Wout4 = (const float*)d_in[19];
    float* out = (float*)d_out;

    char* p = (char*)d_ws;
    auto alloc = [&](size_t n) { char* r = p; p += (n + 255) & ~(size_t)255; return r; };
    unsigned short* wf  = (unsigned short*)alloc(1024ull * 608 * 2);
    unsigned short* wv  = (unsigned short*)alloc(1024ull * 768 * 2);
    unsigned short* Cf  = (unsigned short*)alloc(16384ull * 1024 * 2);
    unsigned short* Cv  = (unsigned short*)alloc(8192ull * 1024 * 2);
    float* W1p   = (float*)alloc(768ull * 1792 * 4);
    float* feats = (float*)alloc(64ull * 1792 * 4);
    float* qbuf  = (float*)alloc(2ull * 64 * 512 * 4);     // f_q_p | v_q_p (zeroed in prep)
    float* f_q_p = qbuf;
    float* v_q_p = qbuf + 64 * 512;
    float* a_q_p = (float*)alloc(64ull * 512 * 4);
    float* a_v   = (float*)alloc(64ull * 512 * 4);
    float* fvc   = (float*)alloc(2ull * 64 * 512 * 4);     // fc | vc (zeroed in scores)
    float* fcb   = fvc;
    float* vcb   = fvc + 64 * 512;
    float* hacc  = (float*)alloc(81920ull * 4);            // h1acc (64*768) | h2acc (64*512)
    float* h1acc = hacc;
    float* h2acc = hacc + 64 * 768;
    float* sbuf  = (float*)alloc(24576ull * 4);            // f scores | v scores
    float* zbuf  = (float*)alloc(64ull * 4);               // zeros for OOB staging lanes

    prep_kernel<<<NPREPB + 64, 256, 0, stream>>>(Wfk, Wfv, Wvk, Wvv, Wout1, audios, Wav,
                                                 wf, wv, W1p, hacc, qbuf, a_v, a_q_p, zbuf);
    gemm_fused<<<1024, 256, 0, stream>>>(frames, 600, 19, wf, 608, Cf, f_q_p, 8, zbuf);
    gemm_fused<<<512, 256, 0, stream>>>(vecs, 768, 24, wv, 768, Cv, v_q_p, 7, zbuf);
    for (int i = 0; i < 2; ++i) {
        scores_kernel<<<6144, 256, 0, stream>>>(Cf, Cv, v_q_p, sbuf, fvc);
        pv_kernel<<<768, 256, 0, stream>>>(Cf, Cv, sbuf, fcb, vcb);
        update_kernel<<<192, 256, 0, stream>>>(Wff_f, Wff_v, Wff_a, i, fcb, vcb, a_v,
                                               f_q_p, v_q_p, a_q_p);
    }
    normfeats_kernel<<<64, 512, 0, stream>>>(a_q_p, f_q_p, v_q_p, metas, feats);
    gemvb_kernel<<<336, 256, 0, stream>>>(feats, 1792, 0, W1p, 1792, h1acc, 768, 12, 14);
    gemvb_kernel<<<96, 256, 0, stream>>>(h1acc, 768, 1, Wout2, 768, h2acc, 512, 8, 6);
    mlp34_kernel<<<64, 256, 0, stream>>>(h2acc, Wout3, Wout4, out);
}